// Round 3
// baseline (126.047 us; speedup 1.0000x reference)
//
#include <hip/hip_runtime.h>
#include <hip/hip_bf16.h>

#define TOKENS 8192
#define D_IN   256
#define HDIM   1024
#define ODIM   768
#define KPACK  1056   // 4*256 data cols + 32 pad block (first 4 = bias coeff)

typedef short bf16x8 __attribute__((ext_vector_type(8)));
typedef float f32x4  __attribute__((ext_vector_type(4)));

static __device__ __forceinline__ ushort f2b(float f) {
    union { __hip_bfloat16 b; ushort u; } cv;
    cv.b = __float2bfloat16(f);
    return cv.u;
}

// direct global->LDS DMA, 16B per lane; LDS dest is wave-uniform base + lane*16
static __device__ __forceinline__ void stage16(const ushort* g, ushort* l) {
    __builtin_amdgcn_global_load_lds(
        (const __attribute__((address_space(1))) void*)g,
        (__attribute__((address_space(3))) void*)l, 16, 0, 0);
}

// tanh-form GELU (max dev from exact erf-GELU ~3e-4)
static __device__ __forceinline__ float gelu_f(float v) {
    float y = 0.7978845608f * v * (1.f + 0.044715f * v * v);
    return v - v / (__expf(2.f * y) + 1.f);
}

// ---- K0a: per-(expert,token) combine weight --------------------------------
__global__ __launch_bounds__(256) void k_route(
    const float* __restrict__ ew, const int* __restrict__ ei,
    float* __restrict__ wmap) {
    int n = blockIdx.x * 256 + threadIdx.x;
    if (n >= TOKENS) return;
    int   i0 = ei[2 * n], i1 = ei[2 * n + 1];
    float w0 = ew[2 * n], w1 = ew[2 * n + 1];
    bool v0 = (unsigned)i0 < 4u, v1 = (unsigned)i1 < 4u;
    float rs = (v0 ? w0 : 0.f) + (v1 ? w1 : 0.f);
    if (rs == 0.f) rs = 1.f;
    float o0 = v0 ? w0 / rs : 0.f;
    float o1 = v1 ? w1 / rs : 0.f;
#pragma unroll
    for (int e = 0; e < 4; ++e) {
        float m = 0.f;
        if (v0 && i0 == e) m += o0;
        if (v1 && i1 == e) m += o1;
        wmap[e * TOKENS + n] = m;
    }
}

// ---- K0b: pack A'' (bf16, swizzled: 16B-chunk index ^= (n>>1)&3) -----------
__global__ __launch_bounds__(256) void k_pack_a(
    const float* __restrict__ xf, const float* __restrict__ wmap,
    ushort* __restrict__ Ap) {
    int gid = blockIdx.x * 256 + threadIdx.x;   // 8192*132 items
    int n  = gid / 132;
    int c8 = gid - n * 132;
    ushort o[8] __attribute__((aligned(16))) = {0, 0, 0, 0, 0, 0, 0, 0};
    if (c8 < 128) {
        int e  = c8 >> 5;
        int d0 = (c8 & 31) << 3;
        float w = wmap[e * TOKENS + n];
        bool keep = (d0 & 127) < 32 * (e + 1);
        if (w != 0.f && keep) {
            const float* s = xf + ((size_t)e * TOKENS + n) * D_IN + d0;
#pragma unroll
            for (int j = 0; j < 8; ++j) {
                float v = s[j];
                if (!(v == v)) v = 0.f;   // nan_to_num
                o[j] = f2b(w * v);
            }
        }
    } else if (c8 == 128) {
#pragma unroll
        for (int j = 0; j < 4; ++j) o[j] = f2b(wmap[j * TOKENS + n]);
    }
    int c8s = (c8 & ~3) | ((c8 & 3) ^ ((n >> 1) & 3));
    *(uint4*)(Ap + (size_t)n * KPACK + c8s * 8) = *(const uint4*)o;
}

// ---- K0c: pack B'' = [W_hid;W_res], bias in K-cols 1024..1027, swizzled ----
__global__ __launch_bounds__(256) void k_pack_b(
    const float* __restrict__ Whid, const float* __restrict__ bhid,
    const float* __restrict__ Wres, const float* __restrict__ bres,
    ushort* __restrict__ Bp) {
    int gid = blockIdx.x * 256 + threadIdx.x;   // 1792*132 items
    int o_ = gid / 132;
    int c8 = gid - o_ * 132;
    ushort v[8] __attribute__((aligned(16))) = {0, 0, 0, 0, 0, 0, 0, 0};
    if (c8 < 128) {
        int e  = c8 >> 5;
        int d0 = (c8 & 31) << 3;
        const float* s = (o_ < HDIM)
            ? Whid + ((size_t)e * HDIM + o_) * D_IN + d0
            : Wres + ((size_t)e * ODIM + (o_ - HDIM)) * D_IN + d0;
#pragma unroll
        for (int j = 0; j < 8; ++j) v[j] = f2b(s[j]);
    } else if (c8 == 128) {
#pragma unroll
        for (int j = 0; j < 4; ++j) {
            float b = (o_ < HDIM) ? bhid[j * HDIM + o_] : bres[j * ODIM + (o_ - HDIM)];
            v[j] = f2b(b);
        }
    }
    int c8s = (c8 & ~3) | ((c8 & 3) ^ ((o_ >> 1) & 3));
    *(uint4*)(Bp + (size_t)o_ * KPACK + c8s * 8) = *(const uint4*)v;
}

// ---- K0d: W_out f32 -> bf16 (swizzled) --------------------------------------
__global__ __launch_bounds__(256) void k_pack_wout(
    const float* __restrict__ Wout, ushort* __restrict__ Wb) {
    int gid = blockIdx.x * 256 + threadIdx.x;   // 768*128 items
    int o_ = gid >> 7, d8 = gid & 127;
    const float* s = Wout + (size_t)gid * 8;
    ushort v[8] __attribute__((aligned(16)));
#pragma unroll
    for (int j = 0; j < 8; ++j) v[j] = f2b(s[j]);
    int d8s = d8 ^ ((o_ >> 1) & 3);
    *(uint4*)(Wb + ((size_t)o_ * 128 + d8s) * 8) = *(const uint4*)v;
}

// ---- GEMM1: (8192 x 1792) = A''(8192x1056) @ B''^T; 2-phase dbuf pipeline --
__global__ __launch_bounds__(256) void k_gemm1(
    const ushort* __restrict__ A, const ushort* __restrict__ B,
    ushort* __restrict__ hidB, float* __restrict__ outpre) {
    __shared__ __align__(16) ushort As[2][128 * 32];
    __shared__ __align__(16) ushort Bs[2][128 * 32];
    const int tid = threadIdx.x;
    const int lane = tid & 63;
    const int w = tid >> 6;
    const int wm = (w >> 1) * 64, wn = (w & 1) * 64;
    const int bm = blockIdx.x, bn = blockIdx.y;
    const int r = lane & 15, g = lane >> 4;
    const int acol = (g * 8) ^ ((( r >> 1) & 3) << 3);   // swizzled frag col

    const int lr = lane >> 2;
    const ushort* Ag0 = A + (size_t)(bm * 128 + w * 32 + lr) * KPACK + (lane & 3) * 8;
    const ushort* Ag1 = Ag0 + (size_t)16 * KPACK;
    const ushort* Bg0 = B + (size_t)(bn * 128 + w * 32 + lr) * KPACK + (lane & 3) * 8;
    const ushort* Bg1 = Bg0 + (size_t)16 * KPACK;
    const int so0 = (w * 32) * 32, so1 = (w * 32 + 16) * 32;

    // prologue: stage tile 0 into buf 0
    stage16(Ag0, &As[0][so0]);
    stage16(Ag1, &As[0][so1]);
    stage16(Bg0, &Bs[0][so0]);
    stage16(Bg1, &Bs[0][so1]);
    __syncthreads();

    f32x4 acc[4][4] = {};
    int cur = 0;
    for (int kt = 0; kt < KPACK; kt += 32) {
        if (kt + 32 < KPACK) {           // prefetch next tile into other buffer
            int nx = cur ^ 1;
            stage16(Ag0 + kt + 32, &As[nx][so0]);
            stage16(Ag1 + kt + 32, &As[nx][so1]);
            stage16(Bg0 + kt + 32, &Bs[nx][so0]);
            stage16(Bg1 + kt + 32, &Bs[nx][so1]);
        }
        bf16x8 af[4], bfr[4];
#pragma unroll
        for (int i = 0; i < 4; ++i)
            af[i] = *(const bf16x8*)&As[cur][(wm + i * 16 + r) * 32 + acol];
#pragma unroll
        for (int j = 0; j < 4; ++j)
            bfr[j] = *(const bf16x8*)&Bs[cur][(wn + j * 16 + r) * 32 + acol];
#pragma unroll
        for (int i = 0; i < 4; ++i)
#pragma unroll
            for (int j = 0; j < 4; ++j)
                acc[i][j] = __builtin_amdgcn_mfma_f32_16x16x32_bf16(
                    af[i], bfr[j], acc[i][j], 0, 0, 0);
        __syncthreads();                 // drains prefetch; protects buf reuse
        cur ^= 1;
    }
#pragma unroll
    for (int i = 0; i < 4; ++i) {
#pragma unroll
        for (int j = 0; j < 4; ++j) {
            int col = bn * 128 + wn + j * 16 + r;
#pragma unroll
            for (int q = 0; q < 4; ++q) {
                int row = bm * 128 + wm + i * 16 + g * 4 + q;
                float v = acc[i][j][q];
                if (col < HDIM) {
                    int sw = (((g * 4 + q) >> 1) & 3) << 3;   // writer-side swizzle
                    hidB[(size_t)row * HDIM + (col ^ sw)] = f2b(gelu_f(v));
                } else {
                    outpre[(size_t)row * ODIM + (col - HDIM)] = v;
                }
            }
        }
    }
}

// ---- GEMM2: out = hid @ W_out^T + b_out + res; 2-phase dbuf pipeline -------
__global__ __launch_bounds__(256) void k_gemm2(
    const ushort* __restrict__ A, const ushort* __restrict__ B,
    const float* __restrict__ bout, float* __restrict__ outpre) {
    __shared__ __align__(16) ushort As[2][128 * 32];
    __shared__ __align__(16) ushort Bs[2][128 * 32];
    const int tid = threadIdx.x;
    const int lane = tid & 63;
    const int w = tid >> 6;
    const int wm = (w >> 1) * 64, wn = (w & 1) * 64;
    const int bm = blockIdx.x, bn = blockIdx.y;
    const int r = lane & 15, g = lane >> 4;
    const int acol = (g * 8) ^ (((r >> 1) & 3) << 3);

    const int lr = lane >> 2;
    const ushort* Ag0 = A + (size_t)(bm * 128 + w * 32 + lr) * HDIM + (lane & 3) * 8;
    const ushort* Ag1 = Ag0 + (size_t)16 * HDIM;
    const ushort* Bg0 = B + (size_t)(bn * 128 + w * 32 + lr) * HDIM + (lane & 3) * 8;
    const ushort* Bg1 = Bg0 + (size_t)16 * HDIM;
    const int so0 = (w * 32) * 32, so1 = (w * 32 + 16) * 32;

    stage16(Ag0, &As[0][so0]);
    stage16(Ag1, &As[0][so1]);
    stage16(Bg0, &Bs[0][so0]);
    stage16(Bg1, &Bs[0][so1]);
    __syncthreads();

    f32x4 acc[4][4] = {};
    int cur = 0;
    for (int kt = 0; kt < HDIM; kt += 32) {
        if (kt + 32 < HDIM) {
            int nx = cur ^ 1;
            stage16(Ag0 + kt + 32, &As[nx][so0]);
            stage16(Ag1 + kt + 32, &As[nx][so1]);
            stage16(Bg0 + kt + 32, &Bs[nx][so0]);
            stage16(Bg1 + kt + 32, &Bs[nx][so1]);
        }
        bf16x8 af[4], bfr[4];
#pragma unroll
        for (int i = 0; i < 4; ++i)
            af[i] = *(const bf16x8*)&As[cur][(wm + i * 16 + r) * 32 + acol];
#pragma unroll
        for (int j = 0; j < 4; ++j)
            bfr[j] = *(const bf16x8*)&Bs[cur][(wn + j * 16 + r) * 32 + acol];
#pragma unroll
        for (int i = 0; i < 4; ++i)
#pragma unroll
            for (int j = 0; j < 4; ++j)
                acc[i][j] = __builtin_amdgcn_mfma_f32_16x16x32_bf16(
                    af[i], bfr[j], acc[i][j], 0, 0, 0);
        __syncthreads();
        cur ^= 1;
    }
#pragma unroll
    for (int i = 0; i < 4; ++i) {
#pragma unroll
        for (int j = 0; j < 4; ++j) {
            int col = bn * 128 + wn + j * 16 + r;
#pragma unroll
            for (int q = 0; q < 4; ++q) {
                int row = bm * 128 + wm + i * 16 + g * 4 + q;
                size_t idx = (size_t)row * ODIM + col;
                outpre[idx] = acc[i][j][q] + bout[col] + outpre[idx];
            }
        }
    }
}

// ---- RMS norm row-wise ------------------------------------------------------
__global__ __launch_bounds__(256) void k_rms(
    const float* __restrict__ outpre, const float* __restrict__ lnw,
    float* __restrict__ out) {
    int row = blockIdx.x, t = threadIdx.x;
    const float* p = outpre + (size_t)row * ODIM;
    float v0 = p[t], v1 = p[t + 256], v2 = p[t + 512];
    float s = v0 * v0 + v1 * v1 + v2 * v2;
#pragma unroll
    for (int off = 32; off > 0; off >>= 1) s += __shfl_down(s, off, 64);
    __shared__ float ws4[4];
    if ((t & 63) == 0) ws4[t >> 6] = s;
    __syncthreads();
    float tot = ws4[0] + ws4[1] + ws4[2] + ws4[3];
    float sc = rsqrtf(tot * (1.f / 768.f) + 1e-6f);
    out[(size_t)row * ODIM + t]       = lnw[t]       * v0 * sc;
    out[(size_t)row * ODIM + t + 256] = lnw[t + 256] * v1 * sc;
    out[(size_t)row * ODIM + t + 512] = lnw[t + 512] * v2 * sc;
}

extern "C" void kernel_launch(void* const* d_in, const int* in_sizes, int n_in,
                              void* d_out, int out_size, void* d_ws, size_t ws_size,
                              hipStream_t stream) {
    const float* ew   = (const float*)d_in[2];
    const int*   ei   = (const int*)d_in[3];
    const float* xf   = (const float*)d_in[4];
    const float* Whid = (const float*)d_in[5];
    const float* bhid = (const float*)d_in[6];
    const float* Wout = (const float*)d_in[7];
    const float* bout = (const float*)d_in[8];
    const float* Wres = (const float*)d_in[9];
    const float* bres = (const float*)d_in[10];
    const float* lnw  = (const float*)d_in[11];

    char* ws = (char*)d_ws;
    float*  wmap   = (float*)(ws);                   // 4*8192*4      = 131072
    ushort* Ap     = (ushort*)(ws + 131072);         // 8192*1056*2   = 17301504
    ushort* Bp     = (ushort*)(ws + 17432576);       // 1792*1056*2   = 3784704
    ushort* Wb     = (ushort*)(ws + 21217280);       // 768*1024*2    = 1572864
    ushort* hidB   = (ushort*)(ws + 22790144);       // 8192*1024*2   = 16777216
    float*  outpre = (float*)(ws + 39567360);        // 8192*768*4    = 25165824

    k_route<<<32, 256, 0, stream>>>(ew, ei, wmap);
    k_pack_a<<<4224, 256, 0, stream>>>(xf, wmap, Ap);
    k_pack_b<<<924, 256, 0, stream>>>(Whid, bhid, Wres, bres, Bp);
    k_pack_wout<<<384, 256, 0, stream>>>(Wout, Wb);
    k_gemm1<<<dim3(64, 14), 256, 0, stream>>>(Ap, Bp, hidB, outpre);
    k_gemm2<<<dim3(64, 6), 256, 0, stream>>>(hidB, Wb, bout, outpre);
    k_rms<<<8192, 256, 0, stream>>>(outpre, lnw, (float*)d_out);
}

// Round 4
// 101.666 us; speedup vs baseline: 1.2398x; 1.2398x over previous
//
#include <hip/hip_runtime.h>
#include <hip/hip_bf16.h>

#define TOKENS 8192
#define D_IN   256
#define HDIM   1024
#define ODIM   768
#define KPACK  1088   // 4*256 data cols + bias chunk + zero pad -> 17 x BK=64
#define NCHUNK 136    // KPACK/8

typedef short bf16x8 __attribute__((ext_vector_type(8)));
typedef float f32x4  __attribute__((ext_vector_type(4)));

static __device__ __forceinline__ ushort f2b(float f) {
    union { __hip_bfloat16 b; ushort u; } cv;
    cv.b = __float2bfloat16(f);
    return cv.u;
}

// direct global->LDS DMA, 16B/lane; LDS dest = wave-uniform base + lane*16
static __device__ __forceinline__ void stage16(const ushort* g, ushort* l) {
    __builtin_amdgcn_global_load_lds(
        (const __attribute__((address_space(1))) void*)g,
        (__attribute__((address_space(3))) void*)l, 16, 0, 0);
}

// tanh-form GELU (max dev from exact erf-GELU ~3e-4)
static __device__ __forceinline__ float gelu_f(float v) {
    float y = 0.7978845608f * v * (1.f + 0.044715f * v * v);
    return v - v / (__expf(2.f * y) + 1.f);
}

// ---- K0a: per-(expert,token) combine weight --------------------------------
__global__ __launch_bounds__(256) void k_route(
    const float* __restrict__ ew, const int* __restrict__ ei,
    float* __restrict__ wmap) {
    int n = blockIdx.x * 256 + threadIdx.x;
    if (n >= TOKENS) return;
    int   i0 = ei[2 * n], i1 = ei[2 * n + 1];
    float w0 = ew[2 * n], w1 = ew[2 * n + 1];
    bool v0 = (unsigned)i0 < 4u, v1 = (unsigned)i1 < 4u;
    float rs = (v0 ? w0 : 0.f) + (v1 ? w1 : 0.f);
    if (rs == 0.f) rs = 1.f;
    float o0 = v0 ? w0 / rs : 0.f;
    float o1 = v1 ? w1 / rs : 0.f;
#pragma unroll
    for (int e = 0; e < 4; ++e) {
        float m = 0.f;
        if (v0 && i0 == e) m += o0;
        if (v1 && i1 == e) m += o1;
        wmap[e * TOKENS + n] = m;
    }
}

// ---- K0b: pack A'' (bf16, PLAIN row-major, zero-padded to KPACK) -----------
__global__ __launch_bounds__(256) void k_pack_a(
    const float* __restrict__ xf, const float* __restrict__ wmap,
    ushort* __restrict__ Ap) {
    int gid = blockIdx.x * 256 + threadIdx.x;   // 8192*136 items
    int n  = gid / NCHUNK;
    int c8 = gid - n * NCHUNK;
    ushort o[8] __attribute__((aligned(16))) = {0, 0, 0, 0, 0, 0, 0, 0};
    if (c8 < 128) {
        int e  = c8 >> 5;
        int d0 = (c8 & 31) << 3;
        float w = wmap[e * TOKENS + n];
        bool keep = (d0 & 127) < 32 * (e + 1);
        if (w != 0.f && keep) {
            const float* s = xf + ((size_t)e * TOKENS + n) * D_IN + d0;
#pragma unroll
            for (int j = 0; j < 8; ++j) {
                float v = s[j];
                if (!(v == v)) v = 0.f;   // nan_to_num
                o[j] = f2b(w * v);
            }
        }
    } else if (c8 == 128) {
#pragma unroll
        for (int j = 0; j < 4; ++j) o[j] = f2b(wmap[j * TOKENS + n]);
    }
    *(uint4*)(Ap + (size_t)n * KPACK + c8 * 8) = *(const uint4*)o;
}

// ---- K0c: pack B'' = [W_hid;W_res], bias in K-cols 1024..1027, plain -------
__global__ __launch_bounds__(256) void k_pack_b(
    const float* __restrict__ Whid, const float* __restrict__ bhid,
    const float* __restrict__ Wres, const float* __restrict__ bres,
    ushort* __restrict__ Bp) {
    int gid = blockIdx.x * 256 + threadIdx.x;   // 1792*136 items
    int o_ = gid / NCHUNK;
    int c8 = gid - o_ * NCHUNK;
    ushort v[8] __attribute__((aligned(16))) = {0, 0, 0, 0, 0, 0, 0, 0};
    if (c8 < 128) {
        int e  = c8 >> 5;
        int d0 = (c8 & 31) << 3;
        const float* s = (o_ < HDIM)
            ? Whid + ((size_t)e * HDIM + o_) * D_IN + d0
            : Wres + ((size_t)e * ODIM + (o_ - HDIM)) * D_IN + d0;
#pragma unroll
        for (int j = 0; j < 8; ++j) v[j] = f2b(s[j]);
    } else if (c8 == 128) {
#pragma unroll
        for (int j = 0; j < 4; ++j) {
            float b = (o_ < HDIM) ? bhid[j * HDIM + o_] : bres[j * ODIM + (o_ - HDIM)];
            v[j] = f2b(b);
        }
    }
    *(uint4*)(Bp + (size_t)o_ * KPACK + c8 * 8) = *(const uint4*)v;
}

// ---- K0d: W_out f32 -> bf16 (plain) -----------------------------------------
__global__ __launch_bounds__(256) void k_pack_wout(
    const float* __restrict__ Wout, ushort* __restrict__ Wb) {
    int gid = blockIdx.x * 256 + threadIdx.x;   // 768*128 items
    const float* s = Wout + (size_t)gid * 8;
    ushort v[8] __attribute__((aligned(16)));
#pragma unroll
    for (int j = 0; j < 8; ++j) v[j] = f2b(s[j]);
    *(uint4*)(Wb + (size_t)gid * 8) = *(const uint4*)v;
}

// ---- GEMM1: 256^2 tile, BK=64, 8 waves, 2-deep counted-vmcnt pipeline ------
// A:(8192 x 1088) B'':(1792 x 1088)^T ; epilogue GELU->hidB / raw->outpre
__global__ __launch_bounds__(512, 2) void k_gemm1(
    const ushort* __restrict__ A, const ushort* __restrict__ B,
    ushort* __restrict__ hidB, float* __restrict__ outpre) {
    __shared__ __align__(16) ushort As[2][256 * 64];   // 32KB each buf
    __shared__ __align__(16) ushort Bs[2][256 * 64];
    const int tid = threadIdx.x;
    const int lane = tid & 63, w = tid >> 6;
    const int wr = w >> 2, wc = w & 3;          // 2M x 4N wave grid
    const int r = lane & 15, g = lane >> 4;

    // XCD-bijective block swizzle: 224 blocks = 8 XCD x 28
    int bid  = blockIdx.x;
    int widx = (bid & 7) * 28 + (bid >> 3);
    int bm = widx / 7, bn = widx - bm * 7;

    // staging: 4 issues x (A,B); thread -> row tid>>3, slot tid&7; global chunk
    // pre-swizzled so LDS slot s holds global chunk s ^ (row&7)
    const int srow = tid >> 3;                  // 0..63 within issue
    const int gc   = (tid & 7) ^ (srow & 7);
    const ushort* Ag = A + (size_t)(bm * 256 + srow) * KPACK + gc * 8;
    const ushort* Bg = B + (size_t)(bn * 256 + srow) * KPACK + gc * 8;
    const int ldst = (w * 8) * 64;              // wave-uniform LDS chunk base

#define G1_STAGE(p, kt) do {                                            \
    _Pragma("unroll")                                                   \
    for (int i_ = 0; i_ < 4; ++i_) {                                    \
        stage16(Ag + (size_t)(i_ * 64) * KPACK + (kt), &As[p][ldst + i_ * 64 * 64]); \
        stage16(Bg + (size_t)(i_ * 64) * KPACK + (kt), &Bs[p][ldst + i_ * 64 * 64]); \
    } } while (0)

    G1_STAGE(0, 0);      // tile 0
    G1_STAGE(1, 64);     // tile 1   (16 loads/wave in flight)

    f32x4 acc[8][4] = {};
    const int cA = (wr * 128 + r) * 64;
    const int cB = (wc * 64 + r) * 64;
    const int sx = r & 7;

    int cur = 0;
    for (int t = 0; t < 17; ++t) {
        if (t < 16) asm volatile("s_waitcnt vmcnt(8)" ::: "memory");
        else        asm volatile("s_waitcnt vmcnt(0)" ::: "memory");
        __builtin_amdgcn_s_barrier();
        const ushort* Ab = As[cur];
        const ushort* Bb = Bs[cur];
#pragma unroll
        for (int kh = 0; kh < 2; ++kh) {
            const int cs = ((kh * 4 + g) ^ sx) * 8;
            bf16x8 bfr[4];
#pragma unroll
            for (int j = 0; j < 4; ++j)
                bfr[j] = *(const bf16x8*)&Bb[cB + j * 16 * 64 + cs];
#pragma unroll
            for (int rh = 0; rh < 2; ++rh) {
                bf16x8 af[4];
#pragma unroll
                for (int i = 0; i < 4; ++i)
                    af[i] = *(const bf16x8*)&Ab[cA + (rh * 64 + i * 16) * 64 + cs];
                __builtin_amdgcn_s_setprio(1);
#pragma unroll
                for (int i = 0; i < 4; ++i)
#pragma unroll
                    for (int j = 0; j < 4; ++j)
                        acc[rh * 4 + i][j] = __builtin_amdgcn_mfma_f32_16x16x32_bf16(
                            af[i], bfr[j], acc[rh * 4 + i][j], 0, 0, 0);
                __builtin_amdgcn_s_setprio(0);
            }
        }
        asm volatile("s_waitcnt lgkmcnt(0)" ::: "memory");
        __builtin_amdgcn_s_barrier();
        if (t + 2 < 17) G1_STAGE(cur, (t + 2) * 64);
        cur ^= 1;
    }
#undef G1_STAGE

#pragma unroll
    for (int fi = 0; fi < 8; ++fi) {
#pragma unroll
        for (int j = 0; j < 4; ++j) {
            int col = bn * 256 + wc * 64 + j * 16 + r;
#pragma unroll
            for (int q = 0; q < 4; ++q) {
                int row = bm * 256 + wr * 128 + fi * 16 + g * 4 + q;
                float v = acc[fi][j][q];
                if (col < HDIM) {
                    hidB[(size_t)row * HDIM + col] = f2b(gelu_f(v));
                } else {
                    outpre[(size_t)row * ODIM + (col - HDIM)] = v;
                }
            }
        }
    }
}

// ---- GEMM2: 128^2 tile, BK=64, 4 waves, same pipeline ----------------------
__global__ __launch_bounds__(256, 2) void k_gemm2(
    const ushort* __restrict__ A, const ushort* __restrict__ B,
    const float* __restrict__ bout, float* __restrict__ outpre) {
    __shared__ __align__(16) ushort As[2][128 * 64];   // 16KB each buf
    __shared__ __align__(16) ushort Bs[2][128 * 64];
    const int tid = threadIdx.x;
    const int lane = tid & 63, w = tid >> 6;
    const int wr = w >> 1, wc = w & 1;          // 2M x 2N wave grid
    const int r = lane & 15, g = lane >> 4;
    const int bm = blockIdx.x, bn = blockIdx.y;

    const int srow = tid >> 3;                  // 0..31 within issue
    const int gc   = (tid & 7) ^ (srow & 7);
    const ushort* Ag = A + (size_t)(bm * 128 + srow) * HDIM + gc * 8;
    const ushort* Bg = B + (size_t)(bn * 128 + srow) * HDIM + gc * 8;
    const int ldst = (w * 8) * 64;

#define G2_STAGE(p, kt) do {                                            \
    _Pragma("unroll")                                                   \
    for (int i_ = 0; i_ < 4; ++i_) {                                    \
        stage16(Ag + (size_t)(i_ * 32) * HDIM + (kt), &As[p][ldst + i_ * 32 * 64]); \
        stage16(Bg + (size_t)(i_ * 32) * HDIM + (kt), &Bs[p][ldst + i_ * 32 * 64]); \
    } } while (0)

    G2_STAGE(0, 0);
    G2_STAGE(1, 64);

    f32x4 acc[4][4] = {};
    const int cA = (wr * 64 + r) * 64;
    const int cB = (wc * 64 + r) * 64;
    const int sx = r & 7;

    int cur = 0;
    for (int t = 0; t < 16; ++t) {
        if (t < 15) asm volatile("s_waitcnt vmcnt(8)" ::: "memory");
        else        asm volatile("s_waitcnt vmcnt(0)" ::: "memory");
        __builtin_amdgcn_s_barrier();
        const ushort* Ab = As[cur];
        const ushort* Bb = Bs[cur];
#pragma unroll
        for (int kh = 0; kh < 2; ++kh) {
            const int cs = ((kh * 4 + g) ^ sx) * 8;
            bf16x8 bfr[4], af[4];
#pragma unroll
            for (int j = 0; j < 4; ++j)
                bfr[j] = *(const bf16x8*)&Bb[cB + j * 16 * 64 + cs];
#pragma unroll
            for (int i = 0; i < 4; ++i)
                af[i] = *(const bf16x8*)&Ab[cA + i * 16 * 64 + cs];
            __builtin_amdgcn_s_setprio(1);
#pragma unroll
            for (int i = 0; i < 4; ++i)
#pragma unroll
                for (int j = 0; j < 4; ++j)
                    acc[i][j] = __builtin_amdgcn_mfma_f32_16x16x32_bf16(
                        af[i], bfr[j], acc[i][j], 0, 0, 0);
            __builtin_amdgcn_s_setprio(0);
        }
        asm volatile("s_waitcnt lgkmcnt(0)" ::: "memory");
        __builtin_amdgcn_s_barrier();
        if (t + 2 < 16) G2_STAGE(cur, (t + 2) * 64);
        cur ^= 1;
    }
#undef G2_STAGE

#pragma unroll
    for (int fi = 0; fi < 4; ++fi) {
#pragma unroll
        for (int j = 0; j < 4; ++j) {
            int col = bn * 128 + wc * 64 + j * 16 + r;
#pragma unroll
            for (int q = 0; q < 4; ++q) {
                int row = bm * 128 + wr * 64 + fi * 16 + g * 4 + q;
                size_t idx = (size_t)row * ODIM + col;
                outpre[idx] = acc[fi][j][q] + bout[col] + outpre[idx];
            }
        }
    }
}

// ---- RMS norm row-wise ------------------------------------------------------
__global__ __launch_bounds__(256) void k_rms(
    const float* __restrict__ outpre, const float* __restrict__ lnw,
    float* __restrict__ out) {
    int row = blockIdx.x, t = threadIdx.x;
    const float* p = outpre + (size_t)row * ODIM;
    float v0 = p[t], v1 = p[t + 256], v2 = p[t + 512];
    float s = v0 * v0 + v1 * v1 + v2 * v2;
#pragma unroll
    for (int off = 32; off > 0; off >>= 1) s += __shfl_down(s, off, 64);
    __shared__ float ws4[4];
    if ((t & 63) == 0) ws4[t >> 6] = s;
    __syncthreads();
    float tot = ws4[0] + ws4[1] + ws4[2] + ws4[3];
    float sc = rsqrtf(tot * (1.f / 768.f) + 1e-6f);
    out[(size_t)row * ODIM + t]       = lnw[t]       * v0 * sc;
    out[(size_t)row * ODIM + t + 256] = lnw[t + 256] * v1 * sc;
    out[(size_t)row * ODIM + t + 512] = lnw[t + 512] * v2 * sc;
}

extern "C" void kernel_launch(void* const* d_in, const int* in_sizes, int n_in,
                              void* d_out, int out_size, void* d_ws, size_t ws_size,
                              hipStream_t stream) {
    const float* ew   = (const float*)d_in[2];
    const int*   ei   = (const int*)d_in[3];
    const float* xf   = (const float*)d_in[4];
    const float* Whid = (const float*)d_in[5];
    const float* bhid = (const float*)d_in[6];
    const float* Wout = (const float*)d_in[7];
    const float* bout = (const float*)d_in[8];
    const float* Wres = (const float*)d_in[9];
    const float* bres = (const float*)d_in[10];
    const float* lnw  = (const float*)d_in[11];

    char* ws = (char*)d_ws;
    float*  wmap   = (float*)(ws);                   // 131072
    ushort* Ap     = (ushort*)(ws + 131072);         // 8192*1088*2 = 17825792
    ushort* Bp     = (ushort*)(ws + 17956864);       // 1792*1088*2 = 3899392
    ushort* Wb     = (ushort*)(ws + 21856256);       // 768*1024*2  = 1572864
    ushort* hidB   = (ushort*)(ws + 23429120);       // 8192*1024*2 = 16777216
    float*  outpre = (float*)(ws + 40206336);        // 8192*768*4  = 25165824
                                                     // end ~62.3MB

    k_route<<<32, 256, 0, stream>>>(ew, ei, wmap);
    k_pack_a<<<4352, 256, 0, stream>>>(xf, wmap, Ap);
    k_pack_b<<<952, 256, 0, stream>>>(Whid, bhid, Wres, bres, Bp);
    k_pack_wout<<<384, 256, 0, stream>>>(Wout, Wb);
    k_gemm1<<<224, 512, 0, stream>>>(Ap, Bp, hidB, outpre);
    k_gemm2<<<dim3(64, 6), 256, 0, stream>>>(hidB, Wb, bout, outpre);
    k_rms<<<8192, 256, 0, stream>>>(outpre, lnw, (float*)d_out);
}

// Round 6
// 98.358 us; speedup vs baseline: 1.2815x; 1.0336x over previous
//
#include <hip/hip_runtime.h>
#include <hip/hip_bf16.h>

#define TOKENS 8192
#define D_IN   256
#define HDIM   1024
#define ODIM   768
#define KPACK  1088   // 4*256 data cols + bias chunk + zero pad -> 17 x BK=64
#define NCHUNK 136    // KPACK/8

typedef short bf16x8 __attribute__((ext_vector_type(8)));
typedef float f32x4  __attribute__((ext_vector_type(4)));

static __device__ __forceinline__ ushort f2b(float f) {
    union { __hip_bfloat16 b; ushort u; } cv;
    cv.b = __float2bfloat16(f);
    return cv.u;
}

// direct global->LDS DMA, 16B/lane; LDS dest = wave-uniform base + lane*16
static __device__ __forceinline__ void stage16(const ushort* g, ushort* l) {
    __builtin_amdgcn_global_load_lds(
        (const __attribute__((address_space(1))) void*)g,
        (__attribute__((address_space(3))) void*)l, 16, 0, 0);
}

// tanh-form GELU (max dev from exact erf-GELU ~3e-4)
static __device__ __forceinline__ float gelu_f(float v) {
    float y = 0.7978845608f * v * (1.f + 0.044715f * v * v);
    return v - v / (__expf(2.f * y) + 1.f);
}

// ---- K0a: per-(expert,token) combine weight --------------------------------
__global__ __launch_bounds__(256) void k_route(
    const float* __restrict__ ew, const int* __restrict__ ei,
    float* __restrict__ wmap) {
    int n = blockIdx.x * 256 + threadIdx.x;
    if (n >= TOKENS) return;
    int   i0 = ei[2 * n], i1 = ei[2 * n + 1];
    float w0 = ew[2 * n], w1 = ew[2 * n + 1];
    bool v0 = (unsigned)i0 < 4u, v1 = (unsigned)i1 < 4u;
    float rs = (v0 ? w0 : 0.f) + (v1 ? w1 : 0.f);
    if (rs == 0.f) rs = 1.f;
    float o0 = v0 ? w0 / rs : 0.f;
    float o1 = v1 ? w1 / rs : 0.f;
#pragma unroll
    for (int e = 0; e < 4; ++e) {
        float m = 0.f;
        if (v0 && i0 == e) m += o0;
        if (v1 && i1 == e) m += o1;
        wmap[e * TOKENS + n] = m;
    }
}

// ---- K0b: pack A'' (bf16, plain row-major, zero-padded to KPACK) -----------
__global__ __launch_bounds__(256) void k_pack_a(
    const float* __restrict__ xf, const float* __restrict__ wmap,
    ushort* __restrict__ Ap) {
    int gid = blockIdx.x * 256 + threadIdx.x;   // 8192*136 items
    int n  = gid / NCHUNK;
    int c8 = gid - n * NCHUNK;
    ushort o[8] __attribute__((aligned(16))) = {0, 0, 0, 0, 0, 0, 0, 0};
    if (c8 < 128) {
        int e  = c8 >> 5;
        int d0 = (c8 & 31) << 3;
        float w = wmap[e * TOKENS + n];
        bool keep = (d0 & 127) < 32 * (e + 1);
        if (w != 0.f && keep) {
            const float* s = xf + ((size_t)e * TOKENS + n) * D_IN + d0;
#pragma unroll
            for (int j = 0; j < 8; ++j) {
                float v = s[j];
                if (!(v == v)) v = 0.f;   // nan_to_num
                o[j] = f2b(w * v);
            }
        }
    } else if (c8 == 128) {
#pragma unroll
        for (int j = 0; j < 4; ++j) o[j] = f2b(wmap[j * TOKENS + n]);
    }
    *(uint4*)(Ap + (size_t)n * KPACK + c8 * 8) = *(const uint4*)o;
}

// ---- K0c: pack B'' = [W_hid;W_res], bias in K-cols 1024..1027, plain -------
__global__ __launch_bounds__(256) void k_pack_b(
    const float* __restrict__ Whid, const float* __restrict__ bhid,
    const float* __restrict__ Wres, const float* __restrict__ bres,
    ushort* __restrict__ Bp) {
    int gid = blockIdx.x * 256 + threadIdx.x;   // 1792*136 items
    int o_ = gid / NCHUNK;
    int c8 = gid - o_ * NCHUNK;
    ushort v[8] __attribute__((aligned(16))) = {0, 0, 0, 0, 0, 0, 0, 0};
    if (c8 < 128) {
        int e  = c8 >> 5;
        int d0 = (c8 & 31) << 3;
        const float* s = (o_ < HDIM)
            ? Whid + ((size_t)e * HDIM + o_) * D_IN + d0
            : Wres + ((size_t)e * ODIM + (o_ - HDIM)) * D_IN + d0;
#pragma unroll
        for (int j = 0; j < 8; ++j) v[j] = f2b(s[j]);
    } else if (c8 == 128) {
#pragma unroll
        for (int j = 0; j < 4; ++j) {
            float b = (o_ < HDIM) ? bhid[j * HDIM + o_] : bres[j * ODIM + (o_ - HDIM)];
            v[j] = f2b(b);
        }
    }
    *(uint4*)(Bp + (size_t)o_ * KPACK + c8 * 8) = *(const uint4*)v;
}

// ---- K0d: W_out f32 -> bf16 (plain) -----------------------------------------
__global__ __launch_bounds__(256) void k_pack_wout(
    const float* __restrict__ Wout, ushort* __restrict__ Wb) {
    int gid = blockIdx.x * 256 + threadIdx.x;   // 768*128 items
    const float* s = Wout + (size_t)gid * 8;
    ushort v[8] __attribute__((aligned(16)));
#pragma unroll
    for (int j = 0; j < 8; ++j) v[j] = f2b(s[j]);
    *(uint4*)(Wb + (size_t)gid * 8) = *(const uint4*)v;
}

// ---- GEMM1: 256^2 tile, BK=64, 8-phase counted-vmcnt schedule --------------
// SAFE SYNC ORDER: every counted vmcnt(N) is followed by a barrier BEFORE any
// wave reads the newly published buffer (vmcnt is per-wave; the barrier makes
// all waves' DMA completion visible). vmcnt sits at the END of p4 / p8.
__global__ __launch_bounds__(512, 2) void k_gemm1(
    const ushort* __restrict__ A, const ushort* __restrict__ B,
    ushort* __restrict__ hidB, float* __restrict__ outpre) {
    __shared__ __align__(16) ushort As[2][256 * 64];   // 32KB each
    __shared__ __align__(16) ushort Bs[2][256 * 64];
    const int tid = threadIdx.x;
    const int lane = tid & 63, w = tid >> 6;
    const int wr = w >> 2, wc = w & 3;          // 2M x 4N wave grid
    const int r = lane & 15, g = lane >> 4;
    const int sx = r & 7;

    // XCD-bijective block swizzle: 224 blocks = 8 XCD x 28
    int bid  = blockIdx.x;
    int widx = (bid & 7) * 28 + (bid >> 3);
    int bm = widx / 7, bn = widx - bm * 7;

    // staging: one call = 512 thr x 16B = 64 rows x 128B;
    // LDS[row][slot] = global[row][slot ^ (row&7)]  (pre-swizzled source)
    const int srow = tid >> 3;                  // 0..63
    const int gc   = (tid & 7) ^ (srow & 7);
    const int wv8  = w * 8;                     // wave-uniform LDS row base
    const ushort* Abase = A + (size_t)(bm * 256) * KPACK;
    const ushort* Bbase = B + (size_t)(bn * 256) * KPACK;

#define STG(gsrc, grow, kc, lds, lrow)                                      \
    stage16((gsrc) + (size_t)((grow) + srow) * KPACK + ((kc) + gc) * 8,     \
            (lds) + ((lrow) + wv8) * 64)

    // prologue: tile0 -> buf0 full (8 calls); tile1 -> buf1 B + A.S0,S2 (6)
    STG(Bbase, 0, 0, &Bs[0][0], 0);     STG(Bbase, 64, 0, &Bs[0][0], 64);
    STG(Bbase, 128, 0, &Bs[0][0], 128); STG(Bbase, 192, 0, &Bs[0][0], 192);
    STG(Abase, 0, 0, &As[0][0], 0);     STG(Abase, 64, 0, &As[0][0], 64);
    STG(Abase, 128, 0, &As[0][0], 128); STG(Abase, 192, 0, &As[0][0], 192);
    STG(Bbase, 0, 8, &Bs[1][0], 0);     STG(Bbase, 64, 8, &Bs[1][0], 64);
    STG(Bbase, 128, 8, &Bs[1][0], 128); STG(Bbase, 192, 8, &Bs[1][0], 192);
    STG(Abase, 0, 8, &As[1][0], 0);     STG(Abase, 128, 8, &As[1][0], 128);
    // publish buf0 (8 oldest done; 6 newest may fly)
    asm volatile("s_waitcnt vmcnt(6)" ::: "memory");
    __builtin_amdgcn_s_barrier();

    f32x4 acc[8][4] = {};
    bf16x8 af[2][2], bfr[4][2];

#define LD_A(buf, mi, ks) (*(const bf16x8*)&As[buf][(wr * 128 + (mi) * 16 + r) * 64 + ((((ks) * 4 + g) ^ sx) * 8)])
#define LD_B(buf, j, ks)  (*(const bf16x8*)&Bs[buf][(wc * 64  + (j) * 16 + r) * 64 + ((((ks) * 4 + g) ^ sx) * 8)])
#define READ_A(buf, q) do {                                                  \
    af[0][0] = LD_A(buf, 2 * (q), 0);     af[0][1] = LD_A(buf, 2 * (q), 1);  \
    af[1][0] = LD_A(buf, 2 * (q) + 1, 0); af[1][1] = LD_A(buf, 2 * (q) + 1, 1); } while (0)
#define READ_B(buf) do { _Pragma("unroll")                                   \
    for (int j_ = 0; j_ < 4; ++j_) { bfr[j_][0] = LD_B(buf, j_, 0); bfr[j_][1] = LD_B(buf, j_, 1); } } while (0)
#define MFMA_Q(q) do {                                                       \
    __builtin_amdgcn_s_setprio(1);                                           \
    _Pragma("unroll") for (int i_ = 0; i_ < 2; ++i_)                         \
    _Pragma("unroll") for (int k_ = 0; k_ < 2; ++k_)                         \
    _Pragma("unroll") for (int j_ = 0; j_ < 4; ++j_)                         \
        acc[2 * (q) + i_][j_] = __builtin_amdgcn_mfma_f32_16x16x32_bf16(     \
            af[i_][k_], bfr[j_][k_], acc[2 * (q) + i_][j_], 0, 0, 0);        \
    __builtin_amdgcn_s_setprio(0); } while (0)
#define PH_SYNC1() do { __builtin_amdgcn_s_barrier();                        \
    asm volatile("s_waitcnt lgkmcnt(0)" ::: "memory"); } while (0)
#define PH_SYNC2() __builtin_amdgcn_s_barrier()

    for (int i = 0; i < 8; ++i) {
        const int kcp = (2 * i + 1) * 8;    // tile 2i+1 -> buf1 A S1,S3
        const int kc0 = (2 * i + 2) * 8;    // tile 2i+2 -> buf0
        const int kc1 = (2 * i + 3) * 8;    // tile 2i+3 -> buf1
        const bool st1 = (i < 7);
        // p1: read buf0 {B, Aq0}; stage buf1.A S1,S3
        READ_B(0); READ_A(0, 0);
        STG(Abase, 64, kcp, &As[1][0], 64);
        STG(Abase, 192, kcp, &As[1][0], 192);
        PH_SYNC1(); MFMA_Q(0); PH_SYNC2();
        // p2: stage buf0.B T0,T1
        READ_A(0, 1);
        STG(Bbase, 0, kc0, &Bs[0][0], 0);
        STG(Bbase, 64, kc0, &Bs[0][0], 64);
        PH_SYNC1(); MFMA_Q(1); PH_SYNC2();
        // p3: stage buf0.B T2,T3
        READ_A(0, 2);
        STG(Bbase, 128, kc0, &Bs[0][0], 128);
        STG(Bbase, 192, kc0, &Bs[0][0], 192);
        PH_SYNC1(); MFMA_Q(2); PH_SYNC2();
        // p4: stage buf0.A S0,S2 ; then publish buf1 (vmcnt covers thru p1)
        READ_A(0, 3);
        STG(Abase, 0, kc0, &As[0][0], 0);
        STG(Abase, 128, kc0, &As[0][0], 128);
        PH_SYNC1(); MFMA_Q(3);
        asm volatile("s_waitcnt vmcnt(6)" ::: "memory");
        PH_SYNC2();
        // p5: read buf1 {B, Aq0}; stage buf0.A S1,S3
        READ_B(1); READ_A(1, 0);
        STG(Abase, 64, kc0, &As[0][0], 64);
        STG(Abase, 192, kc0, &As[0][0], 192);
        PH_SYNC1(); MFMA_Q(0); PH_SYNC2();
        // p6
        READ_A(1, 1);
        if (st1) { STG(Bbase, 0, kc1, &Bs[1][0], 0);
                   STG(Bbase, 64, kc1, &Bs[1][0], 64); }
        PH_SYNC1(); MFMA_Q(1); PH_SYNC2();
        // p7
        READ_A(1, 2);
        if (st1) { STG(Bbase, 128, kc1, &Bs[1][0], 128);
                   STG(Bbase, 192, kc1, &Bs[1][0], 192); }
        PH_SYNC1(); MFMA_Q(2); PH_SYNC2();
        // p8: publish buf0 (vmcnt covers thru p5; full drain before tail)
        READ_A(1, 3);
        if (st1) { STG(Abase, 0, kc1, &As[1][0], 0);
                   STG(Abase, 128, kc1, &As[1][0], 128); }
        PH_SYNC1(); MFMA_Q(3);
        if (st1) asm volatile("s_waitcnt vmcnt(6)" ::: "memory");
        else     asm volatile("s_waitcnt vmcnt(0)" ::: "memory");
        PH_SYNC2();
    }
    // tail: tile 16 from buf0 (published by i=7 p8's vmcnt(0)+barrier);
    // no concurrent writers -> no barriers needed
    READ_B(0); READ_A(0, 0); MFMA_Q(0);
    READ_A(0, 1); MFMA_Q(1);
    READ_A(0, 2); MFMA_Q(2);
    READ_A(0, 3); MFMA_Q(3);
#undef STG
#undef LD_A
#undef LD_B
#undef READ_A
#undef READ_B
#undef MFMA_Q
#undef PH_SYNC1
#undef PH_SYNC2

#pragma unroll
    for (int fi = 0; fi < 8; ++fi) {
#pragma unroll
        for (int j = 0; j < 4; ++j) {
            int col = bn * 256 + wc * 64 + j * 16 + r;
#pragma unroll
            for (int q = 0; q < 4; ++q) {
                int row = bm * 256 + wr * 128 + fi * 16 + g * 4 + q;
                float v = acc[fi][j][q];
                if (col < HDIM) {
                    hidB[(size_t)row * HDIM + col] = f2b(gelu_f(v));
                } else {
                    outpre[(size_t)row * ODIM + (col - HDIM)] = v;
                }
            }
        }
    }
}

// ---- GEMM2: 128^2 tile, BK=64, 4 waves, 2-deep counted pipeline ------------
__global__ __launch_bounds__(256, 2) void k_gemm2(
    const ushort* __restrict__ A, const ushort* __restrict__ B,
    const float* __restrict__ bout, float* __restrict__ outpre) {
    __shared__ __align__(16) ushort As[2][128 * 64];   // 16KB each buf
    __shared__ __align__(16) ushort Bs[2][128 * 64];
    const int tid = threadIdx.x;
    const int lane = tid & 63, w = tid >> 6;
    const int wr = w >> 1, wc = w & 1;          // 2M x 2N wave grid
    const int r = lane & 15, g = lane >> 4;
    const int bm = blockIdx.x, bn = blockIdx.y;

    const int srow = tid >> 3;                  // 0..31 within issue
    const int gc   = (tid & 7) ^ (srow & 7);
    const ushort* Ag = A + (size_t)(bm * 128 + srow) * HDIM + gc * 8;
    const ushort* Bg = B + (size_t)(bn * 128 + srow) * HDIM + gc * 8;
    const int ldst = (w * 8) * 64;

#define G2_STAGE(p, kt) do {                                            \
    _Pragma("unroll")                                                   \
    for (int i_ = 0; i_ < 4; ++i_) {                                    \
        stage16(Ag + (size_t)(i_ * 32) * HDIM + (kt), &As[p][ldst + i_ * 32 * 64]); \
        stage16(Bg + (size_t)(i_ * 32) * HDIM + (kt), &Bs[p][ldst + i_ * 32 * 64]); \
    } } while (0)

    G2_STAGE(0, 0);
    G2_STAGE(1, 64);

    f32x4 acc[4][4] = {};
    const int cA = (wr * 64 + r) * 64;
    const int cB = (wc * 64 + r) * 64;
    const int sx = r & 7;

    int cur = 0;
    for (int t = 0; t < 16; ++t) {
        if (t < 15) asm volatile("s_waitcnt vmcnt(8)" ::: "memory");
        else        asm volatile("s_waitcnt vmcnt(0)" ::: "memory");
        __builtin_amdgcn_s_barrier();
        const ushort* Ab = As[cur];
        const ushort* Bb = Bs[cur];
#pragma unroll
        for (int kh = 0; kh < 2; ++kh) {
            const int cs = ((kh * 4 + g) ^ sx) * 8;
            bf16x8 bfr[4], af[4];
#pragma unroll
            for (int j = 0; j < 4; ++j)
                bfr[j] = *(const bf16x8*)&Bb[cB + j * 16 * 64 + cs];
#pragma unroll
            for (int i = 0; i < 4; ++i)
                af[i] = *(const bf16x8*)&Ab[cA + i * 16 * 64 + cs];
            __builtin_amdgcn_s_setprio(1);
#pragma unroll
            for (int i = 0; i < 4; ++i)
#pragma unroll
                for (int j = 0; j < 4; ++j)
                    acc[i][j] = __builtin_amdgcn_mfma_f32_16x16x32_bf16(
                        af[i], bfr[j], acc[i][j], 0, 0, 0);
            __builtin_amdgcn_s_setprio(0);
        }
        asm volatile("s_waitcnt lgkmcnt(0)" ::: "memory");
        __builtin_amdgcn_s_barrier();
        if (t + 2 < 16) G2_STAGE(cur, (t + 2) * 64);
        cur ^= 1;
    }
#undef G2_STAGE

#pragma unroll
    for (int fi = 0; fi < 4; ++fi) {
#pragma unroll
        for (int j = 0; j < 4; ++j) {
            int col = bn * 128 + wc * 64 + j * 16 + r;
#pragma unroll
            for (int q = 0; q < 4; ++q) {
                int row = bm * 128 + wr * 64 + fi * 16 + g * 4 + q;
                size_t idx = (size_t)row * ODIM + col;
                outpre[idx] = acc[fi][j][q] + bout[col] + outpre[idx];
            }
        }
    }
}

// ---- RMS norm row-wise ------------------------------------------------------
__global__ __launch_bounds__(256) void k_rms(
    const float* __restrict__ outpre, const float* __restrict__ lnw,
    float* __restrict__ out) {
    int row = blockIdx.x, t = threadIdx.x;
    const float* p = outpre + (size_t)row * ODIM;
    float v0 = p[t], v1 = p[t + 256], v2 = p[t + 512];
    float s = v0 * v0 + v1 * v1 + v2 * v2;
#pragma unroll
    for (int off = 32; off > 0; off >>= 1) s += __shfl_down(s, off, 64);
    __shared__ float ws4[4];
    if ((t & 63) == 0) ws4[t >> 6] = s;
    __syncthreads();
    float tot = ws4[0] + ws4[1] + ws4[2] + ws4[3];
    float sc = rsqrtf(tot * (1.f / 768.f) + 1e-6f);
    out[(size_t)row * ODIM + t]       = lnw[t]       * v0 * sc;
    out[(size_t)row * ODIM + t + 256] = lnw[t + 256] * v1 * sc;
    out[(size_t)row * ODIM + t + 512] = lnw[t + 512] * v2 * sc;
}

extern "C" void kernel_launch(void* const* d_in, const int* in_sizes, int n_in,
                              void* d_out, int out_size, void* d_ws, size_t ws_size,
                              hipStream_t stream) {
    const float* ew   = (const float*)d_in[2];
    const int*   ei   = (const int*)d_in[3];
    const float* xf   = (const float*)d_in[4];
    const float* Whid = (const float*)d_in[5];
    const float* bhid = (const float*)d_in[6];
    const float* Wout = (const float*)d_in[7];
    const float* bout = (const float*)d_in[8];
    const float* Wres = (const float*)d_in[9];
    const float* bres = (const float*)d_in[10];
    const float* lnw  = (const float*)d_in[11];

    char* ws = (char*)d_ws;
    float*  wmap   = (float*)(ws);                   // 131072
    ushort* Ap     = (ushort*)(ws + 131072);         // 8192*1088*2 = 17825792
    ushort* Bp     = (ushort*)(ws + 17956864);       // 1792*1088*2 = 3899392
    ushort* Wb     = (ushort*)(ws + 21856256);       // 768*1024*2  = 1572864
    ushort* hidB   = (ushort*)(ws + 23429120);       // 8192*1024*2 = 16777216
    float*  outpre = (float*)(ws + 40206336);        // 8192*768*4  = 25165824

    k_route<<<32, 256, 0, stream>>>(ew, ei, wmap);
    k_pack_a<<<4352, 256, 0, stream>>>(xf, wmap, Ap);
    k_pack_b<<<952, 256, 0, stream>>>(Whid, bhid, Wres, bres, Bp);
    k_pack_wout<<<384, 256, 0, stream>>>(Wout, Wb);
    k_gemm1<<<224, 512, 0, stream>>>(Ap, Bp, hidB, outpre);
    k_gemm2<<<dim3(64, 6), 256, 0, stream>>>(hidB, Wb, bout, outpre);
    k_rms<<<8192, 256, 0, stream>>>(outpre, lnw, (float*)d_out);
}

// Round 7
// 96.832 us; speedup vs baseline: 1.3017x; 1.0158x over previous
//
#include <hip/hip_runtime.h>
#include <hip/hip_bf16.h>

#define TOKENS 8192
#define D_IN   256
#define HDIM   1024
#define ODIM   768
#define KPACK  1088   // 4*256 data cols + bias chunk + zero pad -> 17 x BK=64
#define NCHUNK 136    // KPACK/8

typedef short bf16x8 __attribute__((ext_vector_type(8)));
typedef float f32x4  __attribute__((ext_vector_type(4)));

static __device__ __forceinline__ ushort f2b(float f) {
    union { __hip_bfloat16 b; ushort u; } cv;
    cv.b = __float2bfloat16(f);
    return cv.u;
}

// direct global->LDS DMA, 16B/lane; LDS dest = wave-uniform base + lane*16
static __device__ __forceinline__ void stage16(const ushort* g, ushort* l) {
    __builtin_amdgcn_global_load_lds(
        (const __attribute__((address_space(1))) void*)g,
        (__attribute__((address_space(3))) void*)l, 16, 0, 0);
}

// tanh-form GELU (max dev from exact erf-GELU ~3e-4)
static __device__ __forceinline__ float gelu_f(float v) {
    float y = 0.7978845608f * v * (1.f + 0.044715f * v * v);
    return v - v / (__expf(2.f * y) + 1.f);
}

// ---- K0a: per-(expert,token) combine weight --------------------------------
__global__ __launch_bounds__(256) void k_route(
    const float* __restrict__ ew, const int* __restrict__ ei,
    float* __restrict__ wmap) {
    int n = blockIdx.x * 256 + threadIdx.x;
    if (n >= TOKENS) return;
    int   i0 = ei[2 * n], i1 = ei[2 * n + 1];
    float w0 = ew[2 * n], w1 = ew[2 * n + 1];
    bool v0 = (unsigned)i0 < 4u, v1 = (unsigned)i1 < 4u;
    float rs = (v0 ? w0 : 0.f) + (v1 ? w1 : 0.f);
    if (rs == 0.f) rs = 1.f;
    float o0 = v0 ? w0 / rs : 0.f;
    float o1 = v1 ? w1 / rs : 0.f;
#pragma unroll
    for (int e = 0; e < 4; ++e) {
        float m = 0.f;
        if (v0 && i0 == e) m += o0;
        if (v1 && i1 == e) m += o1;
        wmap[e * TOKENS + n] = m;
    }
}

// ---- K0b: pack A'' (bf16, plain row-major, zero-padded to KPACK) -----------
__global__ __launch_bounds__(256) void k_pack_a(
    const float* __restrict__ xf, const float* __restrict__ wmap,
    ushort* __restrict__ Ap) {
    int gid = blockIdx.x * 256 + threadIdx.x;   // 8192*136 items
    int n  = gid / NCHUNK;
    int c8 = gid - n * NCHUNK;
    ushort o[8] __attribute__((aligned(16))) = {0, 0, 0, 0, 0, 0, 0, 0};
    if (c8 < 128) {
        int e  = c8 >> 5;
        int d0 = (c8 & 31) << 3;
        float w = wmap[e * TOKENS + n];
        bool keep = (d0 & 127) < 32 * (e + 1);
        if (w != 0.f && keep) {
            const float* s = xf + ((size_t)e * TOKENS + n) * D_IN + d0;
#pragma unroll
            for (int j = 0; j < 8; ++j) {
                float v = s[j];
                if (!(v == v)) v = 0.f;   // nan_to_num
                o[j] = f2b(w * v);
            }
        }
    } else if (c8 == 128) {
#pragma unroll
        for (int j = 0; j < 4; ++j) o[j] = f2b(wmap[j * TOKENS + n]);
    }
    *(uint4*)(Ap + (size_t)n * KPACK + c8 * 8) = *(const uint4*)o;
}

// ---- K0c: pack B'' = [W_hid;W_res], bias in K-cols 1024..1027, plain -------
__global__ __launch_bounds__(256) void k_pack_b(
    const float* __restrict__ Whid, const float* __restrict__ bhid,
    const float* __restrict__ Wres, const float* __restrict__ bres,
    ushort* __restrict__ Bp) {
    int gid = blockIdx.x * 256 + threadIdx.x;   // 1792*136 items
    int o_ = gid / NCHUNK;
    int c8 = gid - o_ * NCHUNK;
    ushort v[8] __attribute__((aligned(16))) = {0, 0, 0, 0, 0, 0, 0, 0};
    if (c8 < 128) {
        int e  = c8 >> 5;
        int d0 = (c8 & 31) << 3;
        const float* s = (o_ < HDIM)
            ? Whid + ((size_t)e * HDIM + o_) * D_IN + d0
            : Wres + ((size_t)e * ODIM + (o_ - HDIM)) * D_IN + d0;
#pragma unroll
        for (int j = 0; j < 8; ++j) v[j] = f2b(s[j]);
    } else if (c8 == 128) {
#pragma unroll
        for (int j = 0; j < 4; ++j) {
            float b = (o_ < HDIM) ? bhid[j * HDIM + o_] : bres[j * ODIM + (o_ - HDIM)];
            v[j] = f2b(b);
        }
    }
    *(uint4*)(Bp + (size_t)o_ * KPACK + c8 * 8) = *(const uint4*)v;
}

// ---- K0d: W_out f32 -> bf16 (plain) -----------------------------------------
__global__ __launch_bounds__(256) void k_pack_wout(
    const float* __restrict__ Wout, ushort* __restrict__ Wb) {
    int gid = blockIdx.x * 256 + threadIdx.x;   // 768*128 items
    const float* s = Wout + (size_t)gid * 8;
    ushort v[8] __attribute__((aligned(16)));
#pragma unroll
    for (int j = 0; j < 8; ++j) v[j] = f2b(s[j]);
    *(uint4*)(Wb + (size_t)gid * 8) = *(const uint4*)v;
}

// ---- GEMM1: 256^2, BK=64, 8-phase; closing barriers dropped at p2/p3/p6/p7 -
// Correctness-bearing syncs kept: p1/p5 closings (successor stages a region
// last-read in that phase), p4/p8 publish (vmcnt(N) + barrier, memory-clobber
// asm prevents load hoisting past the publish). sched_barrier(0) before each
// opening barrier pins MFMA issue on the correct side of the barrier.
__global__ __launch_bounds__(512, 2) void k_gemm1(
    const ushort* __restrict__ A, const ushort* __restrict__ B,
    ushort* __restrict__ hidB, float* __restrict__ outpre) {
    __shared__ __align__(16) ushort As[2][256 * 64];   // 32KB each
    __shared__ __align__(16) ushort Bs[2][256 * 64];
    const int tid = threadIdx.x;
    const int lane = tid & 63, w = tid >> 6;
    const int wr = w >> 2, wc = w & 3;          // 2M x 4N wave grid
    const int r = lane & 15, g = lane >> 4;
    const int sx = r & 7;

    // XCD-bijective block swizzle: 224 blocks = 8 XCD x 28
    int bid  = blockIdx.x;
    int widx = (bid & 7) * 28 + (bid >> 3);
    int bm = widx / 7, bn = widx - bm * 7;

    // staging: one call = 512 thr x 16B = 64 rows x 128B;
    // LDS[row][slot] = global[row][slot ^ (row&7)]  (pre-swizzled source)
    const int srow = tid >> 3;                  // 0..63
    const int gc   = (tid & 7) ^ (srow & 7);
    const int wv8  = w * 8;                     // wave-uniform LDS row base
    const ushort* Abase = A + (size_t)(bm * 256) * KPACK;
    const ushort* Bbase = B + (size_t)(bn * 256) * KPACK;

#define STG(gsrc, grow, kc, lds, lrow)                                      \
    stage16((gsrc) + (size_t)((grow) + srow) * KPACK + ((kc) + gc) * 8,     \
            (lds) + ((lrow) + wv8) * 64)

    // prologue: tile0 -> buf0 full (8 calls); tile1 -> buf1 B + A.S0,S2 (6)
    STG(Bbase, 0, 0, &Bs[0][0], 0);     STG(Bbase, 64, 0, &Bs[0][0], 64);
    STG(Bbase, 128, 0, &Bs[0][0], 128); STG(Bbase, 192, 0, &Bs[0][0], 192);
    STG(Abase, 0, 0, &As[0][0], 0);     STG(Abase, 64, 0, &As[0][0], 64);
    STG(Abase, 128, 0, &As[0][0], 128); STG(Abase, 192, 0, &As[0][0], 192);
    STG(Bbase, 0, 8, &Bs[1][0], 0);     STG(Bbase, 64, 8, &Bs[1][0], 64);
    STG(Bbase, 128, 8, &Bs[1][0], 128); STG(Bbase, 192, 8, &Bs[1][0], 192);
    STG(Abase, 0, 8, &As[1][0], 0);     STG(Abase, 128, 8, &As[1][0], 128);
    // publish buf0 (8 oldest done; 6 newest may fly)
    asm volatile("s_waitcnt vmcnt(6)" ::: "memory");
    __builtin_amdgcn_s_barrier();

    f32x4 acc[8][4] = {};
    bf16x8 af[2][2], bfr[4][2];

#define LD_A(buf, mi, ks) (*(const bf16x8*)&As[buf][(wr * 128 + (mi) * 16 + r) * 64 + ((((ks) * 4 + g) ^ sx) * 8)])
#define LD_B(buf, j, ks)  (*(const bf16x8*)&Bs[buf][(wc * 64  + (j) * 16 + r) * 64 + ((((ks) * 4 + g) ^ sx) * 8)])
#define READ_A(buf, q) do {                                                  \
    af[0][0] = LD_A(buf, 2 * (q), 0);     af[0][1] = LD_A(buf, 2 * (q), 1);  \
    af[1][0] = LD_A(buf, 2 * (q) + 1, 0); af[1][1] = LD_A(buf, 2 * (q) + 1, 1); } while (0)
#define READ_B(buf) do { _Pragma("unroll")                                   \
    for (int j_ = 0; j_ < 4; ++j_) { bfr[j_][0] = LD_B(buf, j_, 0); bfr[j_][1] = LD_B(buf, j_, 1); } } while (0)
#define MFMA_Q(q) do {                                                       \
    __builtin_amdgcn_s_setprio(1);                                           \
    _Pragma("unroll") for (int i_ = 0; i_ < 2; ++i_)                         \
    _Pragma("unroll") for (int k_ = 0; k_ < 2; ++k_)                         \
    _Pragma("unroll") for (int j_ = 0; j_ < 4; ++j_)                         \
        acc[2 * (q) + i_][j_] = __builtin_amdgcn_mfma_f32_16x16x32_bf16(     \
            af[i_][k_], bfr[j_][k_], acc[2 * (q) + i_][j_], 0, 0, 0);        \
    __builtin_amdgcn_s_setprio(0); } while (0)
#define OPEN_BAR() do { __builtin_amdgcn_sched_barrier(0);                   \
    __builtin_amdgcn_s_barrier(); } while (0)

    for (int i = 0; i < 8; ++i) {
        const int kcp = (2 * i + 1) * 8;    // tile 2i+1 -> buf1 A S1,S3
        const int kc0 = (2 * i + 2) * 8;    // tile 2i+2 -> buf0
        const int kc1 = (2 * i + 3) * 8;    // tile 2i+3 -> buf1
        const bool st1 = (i < 7);
        // p1: read buf0 {B, Aq0}; stage buf1.A S1,S3; closing kept
        READ_B(0); READ_A(0, 0);
        STG(Abase, 64, kcp, &As[1][0], 64);
        STG(Abase, 192, kcp, &As[1][0], 192);
        OPEN_BAR(); MFMA_Q(0); __builtin_amdgcn_s_barrier();
        // p2: stage buf0.B T0,T1 (last read p1 -> p1 closing fences); no closing
        READ_A(0, 1);
        STG(Bbase, 0, kc0, &Bs[0][0], 0);
        STG(Bbase, 64, kc0, &Bs[0][0], 64);
        OPEN_BAR(); MFMA_Q(1);
        // p3: stage buf0.B T2,T3 (fenced by p2 opening); no closing
        READ_A(0, 2);
        STG(Bbase, 128, kc0, &Bs[0][0], 128);
        STG(Bbase, 192, kc0, &Bs[0][0], 192);
        OPEN_BAR(); MFMA_Q(2);
        // p4: stage buf0.A S0,S2 (last read p2 -> p3/p4 openings fence);
        //     publish buf1 (vmcnt covers thru p1)
        READ_A(0, 3);
        STG(Abase, 0, kc0, &As[0][0], 0);
        STG(Abase, 128, kc0, &As[0][0], 128);
        OPEN_BAR(); MFMA_Q(3);
        asm volatile("s_waitcnt vmcnt(6)" ::: "memory");
        __builtin_amdgcn_s_barrier();
        // p5: read buf1 {B, Aq0}; stage buf0.A S1,S3; closing kept
        READ_B(1); READ_A(1, 0);
        STG(Abase, 64, kc0, &As[0][0], 64);
        STG(Abase, 192, kc0, &As[0][0], 192);
        OPEN_BAR(); MFMA_Q(0); __builtin_amdgcn_s_barrier();
        // p6: no closing
        READ_A(1, 1);
        if (st1) { STG(Bbase, 0, kc1, &Bs[1][0], 0);
                   STG(Bbase, 64, kc1, &Bs[1][0], 64); }
        OPEN_BAR(); MFMA_Q(1);
        // p7: no closing
        READ_A(1, 2);
        if (st1) { STG(Bbase, 128, kc1, &Bs[1][0], 128);
                   STG(Bbase, 192, kc1, &Bs[1][0], 192); }
        OPEN_BAR(); MFMA_Q(2);
        // p8: publish buf0 (vmcnt covers thru p5; full drain before tail)
        READ_A(1, 3);
        if (st1) { STG(Abase, 0, kc1, &As[1][0], 0);
                   STG(Abase, 128, kc1, &As[1][0], 128); }
        OPEN_BAR(); MFMA_Q(3);
        if (st1) asm volatile("s_waitcnt vmcnt(6)" ::: "memory");
        else     asm volatile("s_waitcnt vmcnt(0)" ::: "memory");
        __builtin_amdgcn_s_barrier();
    }
    // tail: tile 16 from buf0 (published by i=7 p8); no concurrent writers
    READ_B(0); READ_A(0, 0); MFMA_Q(0);
    READ_A(0, 1); MFMA_Q(1);
    READ_A(0, 2); MFMA_Q(2);
    READ_A(0, 3); MFMA_Q(3);
#undef STG
#undef LD_A
#undef LD_B
#undef READ_A
#undef READ_B
#undef MFMA_Q
#undef OPEN_BAR

#pragma unroll
    for (int fi = 0; fi < 8; ++fi) {
#pragma unroll
        for (int j = 0; j < 4; ++j) {
            int col = bn * 256 + wc * 64 + j * 16 + r;
#pragma unroll
            for (int q = 0; q < 4; ++q) {
                int row = bm * 256 + wr * 128 + fi * 16 + g * 4 + q;
                float v = acc[fi][j][q];
                if (col < HDIM) {
                    hidB[(size_t)row * HDIM + col] = f2b(gelu_f(v));
                } else {
                    outpre[(size_t)row * ODIM + (col - HDIM)] = v;
                }
            }
        }
    }
}

// ---- GEMM2: 128^2 tile, BK=64, 4 waves, 2-deep counted pipeline ------------
__global__ __launch_bounds__(256, 2) void k_gemm2(
    const ushort* __restrict__ A, const ushort* __restrict__ B,
    const float* __restrict__ bout, float* __restrict__ outpre) {
    __shared__ __align__(16) ushort As[2][128 * 64];   // 16KB each buf
    __shared__ __align__(16) ushort Bs[2][128 * 64];
    const int tid = threadIdx.x;
    const int lane = tid & 63, w = tid >> 6;
    const int wr = w >> 1, wc = w & 1;          // 2M x 2N wave grid
    const int r = lane & 15, g = lane >> 4;
    const int bm = blockIdx.x, bn = blockIdx.y;

    const int srow = tid >> 3;                  // 0..31 within issue
    const int gc   = (tid & 7) ^ (srow & 7);
    const ushort* Ag = A + (size_t)(bm * 128 + srow) * HDIM + gc * 8;
    const ushort* Bg = B + (size_t)(bn * 128 + srow) * HDIM + gc * 8;
    const int ldst = (w * 8) * 64;

#define G2_STAGE(p, kt) do {                                            \
    _Pragma("unroll")                                                   \
    for (int i_ = 0; i_ < 4; ++i_) {                                    \
        stage16(Ag + (size_t)(i_ * 32) * HDIM + (kt), &As[p][ldst + i_ * 32 * 64]); \
        stage16(Bg + (size_t)(i_ * 32) * HDIM + (kt), &Bs[p][ldst + i_ * 32 * 64]); \
    } } while (0)

    G2_STAGE(0, 0);
    G2_STAGE(1, 64);

    f32x4 acc[4][4] = {};
    const int cA = (wr * 64 + r) * 64;
    const int cB = (wc * 64 + r) * 64;
    const int sx = r & 7;

    int cur = 0;
    for (int t = 0; t < 16; ++t) {
        if (t < 15) asm volatile("s_waitcnt vmcnt(8)" ::: "memory");
        else        asm volatile("s_waitcnt vmcnt(0)" ::: "memory");
        __builtin_amdgcn_s_barrier();
        const ushort* Ab = As[cur];
        const ushort* Bb = Bs[cur];
#pragma unroll
        for (int kh = 0; kh < 2; ++kh) {
            const int cs = ((kh * 4 + g) ^ sx) * 8;
            bf16x8 bfr[4], af[4];
#pragma unroll
            for (int j = 0; j < 4; ++j)
                bfr[j] = *(const bf16x8*)&Bb[cB + j * 16 * 64 + cs];
#pragma unroll
            for (int i = 0; i < 4; ++i)
                af[i] = *(const bf16x8*)&Ab[cA + i * 16 * 64 + cs];
            __builtin_amdgcn_s_setprio(1);
#pragma unroll
            for (int i = 0; i < 4; ++i)
#pragma unroll
                for (int j = 0; j < 4; ++j)
                    acc[i][j] = __builtin_amdgcn_mfma_f32_16x16x32_bf16(
                        af[i], bfr[j], acc[i][j], 0, 0, 0);
            __builtin_amdgcn_s_setprio(0);
        }
        asm volatile("s_waitcnt lgkmcnt(0)" ::: "memory");
        __builtin_amdgcn_s_barrier();
        if (t + 2 < 16) G2_STAGE(cur, (t + 2) * 64);
        cur ^= 1;
    }
#undef G2_STAGE

#pragma unroll
    for (int fi = 0; fi < 4; ++fi) {
#pragma unroll
        for (int j = 0; j < 4; ++j) {
            int col = bn * 128 + wc * 64 + j * 16 + r;
#pragma unroll
            for (int q = 0; q < 4; ++q) {
                int row = bm * 128 + wr * 64 + fi * 16 + g * 4 + q;
                size_t idx = (size_t)row * ODIM + col;
                outpre[idx] = acc[fi][j][q] + bout[col] + outpre[idx];
            }
        }
    }
}

// ---- RMS norm row-wise ------------------------------------------------------
__global__ __launch_bounds__(256) void k_rms(
    const float* __restrict__ outpre, const float* __restrict__ lnw,
    float* __restrict__ out) {
    int row = blockIdx.x, t = threadIdx.x;
    const float* p = outpre + (size_t)row * ODIM;
    float v0 = p[t], v1 = p[t + 256], v2 = p[t + 512];
    float s = v0 * v0 + v1 * v1 + v2 * v2;
#pragma unroll
    for (int off = 32; off > 0; off >>= 1) s += __shfl_down(s, off, 64);
    __shared__ float ws4[4];
    if ((t & 63) == 0) ws4[t >> 6] = s;
    __syncthreads();
    float tot = ws4[0] + ws4[1] + ws4[2] + ws4[3];
    float sc = rsqrtf(tot * (1.f / 768.f) + 1e-6f);
    out[(size_t)row * ODIM + t]       = lnw[t]       * v0 * sc;
    out[(size_t)row * ODIM + t + 256] = lnw[t + 256] * v1 * sc;
    out[(size_t)row * ODIM + t + 512] = lnw[t + 512] * v2 * sc;
}

extern "C" void kernel_launch(void* const* d_in, const int* in_sizes, int n_in,
                              void* d_out, int out_size, void* d_ws, size_t ws_size,
                              hipStream_t stream) {
    const float* ew   = (const float*)d_in[2];
    const int*   ei   = (const int*)d_in[3];
    const float* xf   = (const float*)d_in[4];
    const float* Whid = (const float*)d_in[5];
    const float* bhid = (const float*)d_in[6];
    const float* Wout = (const float*)d_in[7];
    const float* bout = (const float*)d_in[8];
    const float* Wres = (const float*)d_in[9];
    const float* bres = (const float*)d_in[10];
    const float* lnw  = (const float*)d_in[11];

    char* ws = (char*)d_ws;
    float*  wmap   = (float*)(ws);                   // 131072
    ushort* Ap     = (ushort*)(ws + 131072);         // 8192*1088*2 = 17825792
    ushort* Bp     = (ushort*)(ws + 17956864);       // 1792*1088*2 = 3899392
    ushort* Wb     = (ushort*)(ws + 21856256);       // 768*1024*2  = 1572864
    ushort* hidB   = (ushort*)(ws + 23429120);       // 8192*1024*2 = 16777216
    float*  outpre = (float*)(ws + 40206336);        // 8192*768*4  = 25165824

    k_route<<<32, 256, 0, stream>>>(ew, ei, wmap);
    k_pack_a<<<4352, 256, 0, stream>>>(xf, wmap, Ap);
    k_pack_b<<<952, 256, 0, stream>>>(Whid, bhid, Wres, bres, Bp);
    k_pack_wout<<<384, 256, 0, stream>>>(Wout, Wb);
    k_gemm1<<<224, 512, 0, stream>>>(Ap, Bp, hidB, outpre);
    k_gemm2<<<dim3(64, 6), 256, 0, stream>>>(hidB, Wb, bout, outpre);
    k_rms<<<8192, 256, 0, stream>>>(outpre, lnw, (float*)d_out);
}